// Round 17
// baseline (23268.295 us; speedup 1.0000x reference)
//
#include <hip/hip_runtime.h>

// FeedbackTransformerKV — persistent kernel, round 17 (corrected).
// Base = r12 sync structure (proven best, 11.66ms). Every GEMV is a
// WAVE-LOCAL reduction over column-major packed weights ([col][k8] uint4):
// lane l holds k=8l..8l+7, dot8, shfl_xor reduce, lane0 writes the result.
// Deletes the write-sP/lbar/reduce pattern everywhere (phase A 9->7 lbars,
// B 5->4; ~6 full-block LDS round trips per layer removed). V stored
// transposed (memVT[d][slot] bf16) for lane-contiguous av reads. woT is
// packed PER HEAD: [l][h][512 col][8 k8] over w_out rows h*64..h*64+63.
// Phase-top prefetch of first-pass operands only (~20 regs, in-phase).

#define S_ 128
#define B_ 16
#define D_ 512
#define H_ 8
#define DK_ 64
#define DFF_ 2048
#define L_ 4
#define P_ 4096

#define NBLK 128
#define NTHR 1024

struct FtkvParams {
  const float *x_seq, *w_query, *qpb, *kpe, *w_out, *b_out;
  const float *ln1_g, *ln1_b, *ln2_g, *ln2_b;
  const float *w_ff1, *b_ff1, *w_ff2, *b_ff2;
  const float *norm_g, *norm_b, *comb_w, *w_key, *w_value;
  float *out;
  float *dpart;     // [16 g][8 cs][512]
  float *dpart2;    // [16 g][8 cs][512]
  unsigned *memK;   // [g*8+h][128 slot][32 dw] bf16 pairs
  ushort *memVT;    // [g*8+h][64 d][128 slot] bf16 (TRANSPOSED)
  const uint4 *wqT; // per layer [512 col][64 k8]
  const uint4 *woT; // [l][h][512 col][8 k8]  (rows h*64..h*64+63)
  const uint4 *w1T; // per layer [2048 col][64 k8]
  const uint4 *w2T; // per layer [512 col][256 k8]
  const uint4 *wkT; // [512 col][64 k8]
  const uint4 *wvT; // [512 col][64 k8]
  unsigned int *bar;
};

__device__ __forceinline__ float cload(const float *p_) {
  return __hip_atomic_load(p_, __ATOMIC_RELAXED, __HIP_MEMORY_SCOPE_AGENT);
}
__device__ __forceinline__ void cstore(float *p_, float v) {
  __hip_atomic_store(p_, v, __ATOMIC_RELAXED, __HIP_MEMORY_SCOPE_AGENT);
}

__device__ __forceinline__ float waveRedSum(float v) {
#pragma unroll
  for (int off = 32; off; off >>= 1) v += __shfl_xor(v, off, 64);
  return v;
}
__device__ __forceinline__ float waveRedMax(float v) {
#pragma unroll
  for (int off = 32; off; off >>= 1) v = fmaxf(v, __shfl_xor(v, off, 64));
  return v;
}
__device__ __forceinline__ float red8(float v) {
  v += __shfl_xor(v, 1, 64);
  v += __shfl_xor(v, 2, 64);
  v += __shfl_xor(v, 4, 64);
  return v;
}
__device__ __forceinline__ float red32(float v) {
  v += __shfl_xor(v, 1, 64);
  v += __shfl_xor(v, 2, 64);
  v += __shfl_xor(v, 4, 64);
  v += __shfl_xor(v, 8, 64);
  v += __shfl_xor(v, 16, 64);
  return v;
}

// Light barrier: LDS visibility only; global loads stay in flight.
__device__ __forceinline__ void lbar() {
  asm volatile("s_waitcnt lgkmcnt(0)" ::: "memory");
  __builtin_amdgcn_s_barrier();
}

#define UNPK(w, flo, fhi)                                     \
  float flo = __uint_as_float((unsigned)(w) << 16);           \
  float fhi = __uint_as_float((unsigned)(w) & 0xffff0000u);

__device__ __forceinline__ float dot8(const float *z, uint4 w) {
  UNPK(w.x, a0, a1); UNPK(w.y, b0, b1);
  UNPK(w.z, c0, c1); UNPK(w.w, d0, d1);
  return ((z[0] * a0 + z[1] * a1) + (z[2] * b0 + z[3] * b1)) +
         ((z[4] * c0 + z[5] * c1) + (z[6] * d0 + z[7] * d1));
}

// Group barrier (8 blocks/group): full drain; agent-scope arrive + poll.
__device__ __forceinline__ void gbarN(unsigned *arr, unsigned &epoch) {
  __syncthreads();
  const unsigned e = ++epoch;
  if (threadIdx.x == 0) {
    __hip_atomic_fetch_add(arr, 1u, __ATOMIC_RELAXED,
                           __HIP_MEMORY_SCOPE_AGENT);
    while (__hip_atomic_load(arr, __ATOMIC_RELAXED,
                             __HIP_MEMORY_SCOPE_AGENT) < e * 8u)
      __builtin_amdgcn_s_sleep(1);
  }
  __syncthreads();
}

__global__ void ftkv_init(unsigned *bar) {
  for (int i = threadIdx.x; i < 4096; i += 256) bar[i] = 0u;
}

__device__ __forceinline__ unsigned bf16rne(float x) {
  unsigned b = __float_as_uint(x);
  return (b + 0x7fffu + ((b >> 16) & 1u)) >> 16;
}

// src[K][N] fp32 (row stride N) -> dst packed COLUMN-MAJOR: [n][K/8][4dw]
__global__ void ftkv_packT(const float *src, unsigned *dst, int K, int N) {
  int kd = K / 2;  // dwords per column
  int total = kd * N;
  for (int i = blockIdx.x * blockDim.x + threadIdx.x; i < total;
       i += gridDim.x * blockDim.x) {
    int n = i / kd, rem = i - n * kd;
    int k8 = rem >> 2, q = rem & 3;
    int r0 = 8 * k8 + 2 * q;
    dst[i] = bf16rne(src[(size_t)r0 * N + n]) |
             (bf16rne(src[(size_t)(r0 + 1) * N + n]) << 16);
  }
}

struct Smem {
  float sZ[512];
  float sH[256];
  float sQ[64], sQB[64], sS[128], sRed[24];
};

__device__ __forceinline__ void lnstats(int tid, int lane, int wid, float v,
                                        float *sRed, float &mu, float &rs) {
  lbar();
  if (tid < 512) {
    float s1 = waveRedSum(v), s2 = waveRedSum(v * v);
    if (lane == 0) { sRed[wid] = s1; sRed[8 + wid] = s2; }
  }
  lbar();
  float a = 0.f, c = 0.f;
#pragma unroll
  for (int i = 0; i < 8; ++i) { a += sRed[i]; c += sRed[8 + i]; }
  mu = a * (1.f / 512.f);
  float var = c * (1.f / 512.f) - mu * mu;
  rs = rsqrtf(var + 1e-5f);
}

__global__ __launch_bounds__(NTHR, 4) void ftkv_main(FtkvParams p) {
  const int bid = blockIdx.x;
  const int tid = threadIdx.x;
  const int lane = tid & 63, wv = tid >> 6;
  const int g = bid >> 3;  // batch element (group)
  const int cs = bid & 7;  // col-slice == head

  __shared__ Smem sm;

  unsigned *garr = p.bar + g * 32;
  unsigned gep = 0;

  float cw0 = p.comb_w[0], cw1 = p.comb_w[1], cw2 = p.comb_w[2],
        cw3 = p.comb_w[3], cw4 = p.comb_w[4];
  float cm = fmaxf(fmaxf(fmaxf(cw0, cw1), fmaxf(cw2, cw3)), cw4);
  float e0 = __expf(cw0 - cm), e1 = __expf(cw1 - cm), e2 = __expf(cw2 - cm),
        e3 = __expf(cw3 - cm), e4 = __expf(cw4 - cm);
  float einv = 1.0f / (e0 + e1 + e2 + e3 + e4);
  float comb0 = e0 * einv, comb1 = e1 * einv, comb2 = e2 * einv,
        comb3 = e3 * einv, comb4 = e4 * einv;

  float xr = 0.f, mr = 0.f;
  if (tid < 512) {
    xr = p.x_seq[g * D_ + tid];
    mr = comb0 * xr;
  }

  unsigned *memKb = p.memK + ((size_t)(g * H_ + cs)) * S_ * 32;
  ushort *memVTb = p.memVT + ((size_t)(g * H_ + cs)) * 64 * S_;
  float *dpA = p.dpart + (size_t)g * 8 * 512;
  float *dpB = p.dpart2 + (size_t)g * 8 * 512;

  for (int t = 0; t < S_; ++t) {
    for (int l = 0; l < L_; ++l) {
      const float cl = (l == 1) ? comb1 : (l == 2) ? comb2 : comb3;

      // ---- entry: apply FF(l-1) partials ----
      if (l > 0 && tid < 512) {
        float s = p.b_ff2[(l - 1) * D_ + tid];
#pragma unroll
        for (int c2 = 0; c2 < 8; ++c2) s += cload(dpB + c2 * 512 + tid);
        xr += s;
        mr += cl * xr;
      }

      // =================== Phase A: attention (t>0) =====================
      if (t > 0) {
        const uint4 *wqTl =
            p.wqT + (size_t)l * 512 * 64 + (size_t)(cs * 64) * 64;
        const uint4 *woTl =
            p.woT + ((size_t)l * H_ + cs) * 512 * 8;

        // ---- phase-top prefetch: first-pass operands only ----
        uint4 pfWq = wqTl[(size_t)(wv * 4) * 64 + lane];
        const int jj = lane >> 3, u8 = lane & 7;
        const int jsc = wv * 8 + jj;
        uint4 pfMku = ((const uint4 *)(memKb + (size_t)jsc * 32))[u8];
        int kidx = P_ - t + jsc;
        kidx = kidx < 0 ? 0 : (kidx > P_ - 1 ? P_ - 1 : kidx);
        const float4 *kpp = (const float4 *)(p.kpe +
            (((size_t)l * P_ + kidx) * H_ + cs) * 64 + u8 * 8);
        float4 pfKp0 = kpp[0], pfKp1 = kpp[1];
        unsigned pfMv =
            *(const unsigned *)(memVTb + (size_t)(wv * 4) * S_ + 2 * lane);
        uint4 pfWo = woTl[(size_t)(wv * 32 + jj) * 8 + u8];

        float mu, rs;
        lnstats(tid, lane, wv, xr, sm.sRed, mu, rs);
        if (tid < 512)
          sm.sZ[tid] = (xr - mu) * rs * p.ln1_g[l * D_ + tid] +
                       p.ln1_b[l * D_ + tid];
        lbar();
        // qproj: wave-local, 4 cols/wave
        {
          float qv[4];
#pragma unroll
          for (int c = 0; c < 4; ++c) {
            int col = wv * 4 + c;
            uint4 w = (c == 0) ? pfWq : wqTl[(size_t)col * 64 + lane];
            qv[c] = dot8(&sm.sZ[8 * lane], w);
          }
#pragma unroll
          for (int c = 0; c < 4; ++c) qv[c] = waveRedSum(qv[c]);
          if (lane == 0) {
#pragma unroll
            for (int c = 0; c < 4; ++c) {
              int col = wv * 4 + c;
              sm.sQ[col] = qv[c];
              sm.sQB[col] = qv[c] + p.qpb[(l * H_ + cs) * 64 + col];
            }
          }
        }
        lbar();
        // scores: 8 j per wave, 8-lane reduce (single pass, prefetched)
        {
          UNPK(pfMku.x, k0, k1); UNPK(pfMku.y, k2, k3);
          UNPK(pfMku.z, k4, k5); UNPK(pfMku.w, k6, k7);
          const float *qb = &sm.sQB[u8 * 8], *qr = &sm.sQ[u8 * 8];
          float acc =
              (qb[0] * k0 + qb[1] * k1 + qb[2] * k2 + qb[3] * k3) +
              (qb[4] * k4 + qb[5] * k5 + qb[6] * k6 + qb[7] * k7) +
              (qr[0] * pfKp0.x + qr[1] * pfKp0.y + qr[2] * pfKp0.z +
               qr[3] * pfKp0.w) +
              (qr[4] * pfKp1.x + qr[5] * pfKp1.y + qr[6] * pfKp1.z +
               qr[7] * pfKp1.w);
          acc = red8(acc);
          if (u8 == 0) sm.sS[jsc] = acc;
        }
        lbar();
        // softmax (wave 0, fused mask/scale/max/exp/sum)
        if (tid < 64) {
          float a0 = sm.sS[tid], a1 = sm.sS[tid + 64];
          a0 = (tid < t) ? a0 * 0.125f : -1e30f;
          a1 = (tid + 64 < t) ? a1 * 0.125f : -1e30f;
          float m = waveRedMax(fmaxf(a0, a1));
          float ee0 = __expf(a0 - m), ee1 = __expf(a1 - m);
          float s = waveRedSum(ee0 + ee1);
          sm.sS[tid] = ee0;
          sm.sS[64 + tid] = ee1;
          if (tid == 0) sm.sRed[19] = s;
        }
        lbar();
        // av: wave-local, 4 d/wave (V transposed -> lane-contiguous dwords)
        {
          float av4[4];
#pragma unroll
          for (int c = 0; c < 4; ++c) {
            int d = wv * 4 + c;
            unsigned mv = (c == 0)
                ? pfMv
                : *(const unsigned *)(memVTb + (size_t)d * S_ + 2 * lane);
            UNPK(mv, v0, v1);
            av4[c] = sm.sS[2 * lane] * v0 + sm.sS[2 * lane + 1] * v1;
          }
#pragma unroll
          for (int c = 0; c < 4; ++c) av4[c] = waveRedSum(av4[c]);
          if (lane == 0) {
            float inv = 1.0f / sm.sRed[19];
#pragma unroll
            for (int c = 0; c < 4; ++c) sm.sQ[wv * 4 + c] = av4[c] * inv;
          }
        }
        lbar();
        // Wout partial: 8 cols x 4 passes per wave, 8-lane reduce -> dpA
        {
          float res[4];
#pragma unroll
          for (int pp = 0; pp < 4; ++pp) {
            int col = wv * 32 + pp * 8 + jj;
            uint4 w = (pp == 0) ? pfWo : woTl[(size_t)col * 8 + u8];
            float part = dot8(&sm.sQ[8 * u8], w);
            res[pp] = red8(part);
          }
#pragma unroll
          for (int pp = 0; pp < 4; ++pp)
            if (u8 == 0)
              cstore(dpA + cs * 512 + wv * 32 + pp * 8 + jj, res[pp]);
        }
        gbarN(garr, gep);

        // apply Wout partials
        if (tid < 512) {
          float s = p.b_out[l * D_ + tid];
#pragma unroll
          for (int c2 = 0; c2 < 8; ++c2) s += cload(dpA + c2 * 512 + tid);
          xr += s;
        }
      }

      // =================== Phase B: LN2 + FF1 + FF2 =====================
      {
        const uint4 *w1Tl =
            p.w1T + (size_t)l * 2048 * 64 + (size_t)(cs * 256) * 64;
        const uint4 *w2Tl = p.w2T + (size_t)l * 512 * 256;
        const int csub2 = lane >> 5, u32 = lane & 31;

        uint4 pfW1 = w1Tl[(size_t)wv * 64 + lane];
        uint4 pfW2 =
            w2Tl[(size_t)(wv * 2 + csub2) * 256 + cs * 32 + u32];

        float mu, rs;
        lnstats(tid, lane, wv, xr, sm.sRed, mu, rs);
        if (tid < 512)
          sm.sZ[tid] = (xr - mu) * rs * p.ln2_g[l * D_ + tid] +
                       p.ln2_b[l * D_ + tid];
        lbar();
        // FF1: 1 col/wave x 16 passes, wave reduce -> sH
        {
#pragma unroll
          for (int pp = 0; pp < 16; ++pp) {
            int col = pp * 16 + wv;
            uint4 w = (pp == 0) ? pfW1 : w1Tl[(size_t)col * 64 + lane];
            float part = dot8(&sm.sZ[8 * lane], w);
            part = waveRedSum(part);
            if (lane == 0)
              sm.sH[col] =
                  fmaxf(part + p.b_ff1[l * DFF_ + cs * 256 + col], 0.f);
          }
        }
        lbar();
        // FF2: 2 cols/wave x 16 passes, 32-lane reduce -> dpB
        {
#pragma unroll
          for (int pp = 0; pp < 16; ++pp) {
            int col = pp * 32 + wv * 2 + csub2;
            uint4 w =
                (pp == 0) ? pfW2 : w2Tl[(size_t)col * 256 + cs * 32 + u32];
            float part = dot8(&sm.sH[8 * u32], w);
            part = red32(part);
            if (u32 == 0) cstore(dpB + cs * 512 + col, part);
          }
        }
      }
      gbarN(garr, gep);
    } // layers

    // ====== Phase E (group-local): KV slot t; out[t]; next x ====
    {
      uint4 pfKv = p.wkT[(size_t)(cs * 64 + wv) * 64 + lane];
      if (tid < 512) {
        float s = p.b_ff2[3 * D_ + tid];
#pragma unroll
        for (int c2 = 0; c2 < 8; ++c2) s += cload(dpB + c2 * 512 + tid);
        xr += s;
        mr += comb4 * xr;
        sm.sZ[tid] = mr;
      }
      lbar();
      // KV proj: 1 out/wave x 8 passes (0-63 = K dims, 64-127 = V dims)
      {
#pragma unroll
        for (int pp = 0; pp < 8; ++pp) {
          int o = pp * 16 + wv;
          int c = o & 63;
          const uint4 *wt = (o < 64) ? p.wkT : p.wvT;
          uint4 w = (pp == 0) ? pfKv : wt[(size_t)(cs * 64 + c) * 64 + lane];
          float part = dot8(&sm.sZ[8 * lane], w);
          part = waveRedSum(part);
          if (lane == 0) sm.sS[o] = part;
        }
      }
      lbar();
      if (tid < 32) {
        unsigned pk =
            bf16rne(sm.sS[2 * tid]) | (bf16rne(sm.sS[2 * tid + 1]) << 16);
        memKb[(size_t)t * 32 + tid] = pk;
      } else if (tid >= 64 && tid < 128) {
        int d = tid - 64;
        memVTb[(size_t)d * S_ + t] = (ushort)bf16rne(sm.sS[64 + d]);
      }
      __syncthreads();  // drain KV stores: next step reads them
      float mu, rs;
      lnstats(tid, lane, wv, xr, sm.sRed, mu, rs);
      if (tid < 512 && (tid >> 6) == cs)
        p.out[((size_t)t * B_ + g) * D_ + tid] =
            (xr - mu) * rs * p.norm_g[tid] + p.norm_b[tid];
      if (t + 1 < S_ && tid < 512) {
        xr = p.x_seq[((size_t)(t + 1) * B_ + g) * D_ + tid];
        mr = comb0 * xr;
      }
    }
    // no barrier: E is group-local; next gbarN orders the exchange
  } // t
}

extern "C" void kernel_launch(void *const *d_in, const int *in_sizes, int n_in,
                              void *d_out, int out_size, void *d_ws,
                              size_t ws_size, hipStream_t stream) {
  (void)in_sizes; (void)n_in; (void)out_size; (void)ws_size;

  FtkvParams p;
  p.x_seq  = (const float *)d_in[0];
  p.w_query = (const float *)d_in[1];
  p.qpb    = (const float *)d_in[2];
  p.kpe    = (const float *)d_in[3];
  p.w_out  = (const float *)d_in[4];
  p.b_out  = (const float *)d_in[5];
  p.ln1_g  = (const float *)d_in[6];
  p.ln1_b  = (const float *)d_in[7];
  p.ln2_g  = (const float *)d_in[8];
  p.ln2_b  = (const float *)d_in[9];
  p.w_ff1  = (const float *)d_in[10];
  p.b_ff1  = (const float *)d_in[11];
  p.w_ff2  = (const float *)d_in[12];
  p.b_ff2  = (const float *)d_in[13];
  p.norm_g = (const float *)d_in[14];
  p.norm_b = (const float *)d_in[15];
  p.comb_w = (const float *)d_in[16];
  p.w_key  = (const float *)d_in[17];
  p.w_value = (const float *)d_in[18];
  p.out = (float *)d_out;

  char *ws = (char *)d_ws;
  p.bar = (unsigned int *)ws; // 16KB
  float *f = (float *)(ws + 16384);
  p.dpart  = f; f += B_ * 8 * D_;
  p.dpart2 = f; f += B_ * 8 * D_;
  unsigned *u = (unsigned *)f;
  p.memK = u; u += B_ * H_ * S_ * 32;
  p.memVT = (ushort *)u; u += B_ * H_ * 64 * S_ / 2;
  unsigned *wqT = u; u += L_ * 512 * 256;       // [l][col][k8] dwords
  unsigned *woT = u; u += L_ * H_ * 512 * 32;   // [l][h][col][k8] dwords
  unsigned *w1T = u; u += L_ * 2048 * 256;
  unsigned *w2T = u; u += (size_t)L_ * 512 * 1024;
  unsigned *wkT = u; u += 512 * 256;
  unsigned *wvT = u; u += 512 * 256;
  p.wqT = (const uint4 *)wqT; p.woT = (const uint4 *)woT;
  p.w1T = (const uint4 *)w1T; p.w2T = (const uint4 *)w2T;
  p.wkT = (const uint4 *)wkT; p.wvT = (const uint4 *)wvT;

  ftkv_init<<<dim3(1), dim3(256), 0, stream>>>(p.bar);
  for (int l = 0; l < L_; ++l) {
    ftkv_packT<<<dim3(512), dim3(256), 0, stream>>>(
        p.w_query + (size_t)l * 512 * 512, wqT + (size_t)l * 512 * 256,
        512, 512);
    for (int h = 0; h < H_; ++h)
      ftkv_packT<<<dim3(128), dim3(256), 0, stream>>>(
          p.w_out + ((size_t)l * 512 + h * 64) * 512,
          woT + ((size_t)l * H_ + h) * 512 * 32, 64, 512);
    ftkv_packT<<<dim3(512), dim3(256), 0, stream>>>(
        p.w_ff1 + (size_t)l * 512 * DFF_, w1T + (size_t)l * 2048 * 256,
        512, DFF_);
    ftkv_packT<<<dim3(512), dim3(256), 0, stream>>>(
        p.w_ff2 + (size_t)l * DFF_ * 512, w2T + (size_t)l * 512 * 1024,
        DFF_, 512);
  }
  ftkv_packT<<<dim3(512), dim3(256), 0, stream>>>(p.w_key, wkT, 512, 512);
  ftkv_packT<<<dim3(512), dim3(256), 0, stream>>>(p.w_value, wvT, 512, 512);
  ftkv_main<<<dim3(NBLK), dim3(NTHR), 0, stream>>>(p);
}

// Round 18
// 11759.435 us; speedup vs baseline: 1.9787x; 1.9787x over previous
//
#include <hip/hip_runtime.h>

// FeedbackTransformerKV — persistent kernel, round 18.
// = r12 (proven best, 11.66ms) + r16's fused merge+softmax stage only
// (one lbar + one full-block stage removed; numerically identical in r16).
// r17's wave-local GEMV reverted: its sZ[8*lane] access pattern was an
// 8-way LDS bank conflict on every read (4.35e8 conflicts, 2x time).
// This round locks the best-known structure back in as the final state.

#define S_ 128
#define B_ 16
#define D_ 512
#define H_ 8
#define DK_ 64
#define DFF_ 2048
#define L_ 4
#define P_ 4096

#define NBLK 128
#define NTHR 1024

struct FtkvParams {
  const float *x_seq, *w_query, *qpb, *kpe, *w_out, *b_out;
  const float *ln1_g, *ln1_b, *ln2_g, *ln2_b;
  const float *w_ff1, *b_ff1, *w_ff2, *b_ff2;
  const float *norm_g, *norm_b, *comb_w, *w_key, *w_value;
  float *out;
  float *dpart;     // [16 g][8 cs][512]
  float *dpart2;    // [16 g][8 cs][512]
  unsigned *memK;   // [16 g][8 h][128 slot][32 dw] bf16 pairs
  unsigned *memV;   // [16 g][8 h][128 slot][32 dw]
  const uint4 *wqp;  // per layer [64 k8][512 col] (uint4 = 8 bf16 along k)
  const uint4 *wop;
  const uint4 *w1p;  // per layer [64 k8][2048]
  const uint4 *w2p;  // per layer [256 k8][512]
  const uint4 *wkp;  // [64 k8][512]
  const uint4 *wvp;
  unsigned int *bar;
};

__device__ __forceinline__ float cload(const float *p_) {
  return __hip_atomic_load(p_, __ATOMIC_RELAXED, __HIP_MEMORY_SCOPE_AGENT);
}
__device__ __forceinline__ void cstore(float *p_, float v) {
  __hip_atomic_store(p_, v, __ATOMIC_RELAXED, __HIP_MEMORY_SCOPE_AGENT);
}

__device__ __forceinline__ float waveRedSum(float v) {
#pragma unroll
  for (int off = 32; off; off >>= 1) v += __shfl_xor(v, off, 64);
  return v;
}
__device__ __forceinline__ float waveRedMax(float v) {
#pragma unroll
  for (int off = 32; off; off >>= 1) v = fmaxf(v, __shfl_xor(v, off, 64));
  return v;
}

// Light barrier: LDS visibility only; global loads stay in flight.
__device__ __forceinline__ void lbar() {
  asm volatile("s_waitcnt lgkmcnt(0)" ::: "memory");
  __builtin_amdgcn_s_barrier();
}

#define UNPK(w, flo, fhi)                                     \
  float flo = __uint_as_float((unsigned)(w) << 16);           \
  float fhi = __uint_as_float((unsigned)(w) & 0xffff0000u);

__device__ __forceinline__ float dot8(const float *z, uint4 w) {
  UNPK(w.x, a0, a1); UNPK(w.y, b0, b1);
  UNPK(w.z, c0, c1); UNPK(w.w, d0, d1);
  return ((z[0] * a0 + z[1] * a1) + (z[2] * b0 + z[3] * b1)) +
         ((z[4] * c0 + z[5] * c1) + (z[6] * d0 + z[7] * d1));
}

// Group barrier (8 blocks/group): full drain before arrive; poll arrive ctr.
__device__ __forceinline__ void gbarN(unsigned *arr, unsigned &epoch) {
  __syncthreads();  // drains vmcnt -> sc1 partial stores visible
  const unsigned e = ++epoch;
  if (threadIdx.x == 0) {
    __hip_atomic_fetch_add(arr, 1u, __ATOMIC_RELAXED,
                           __HIP_MEMORY_SCOPE_AGENT);
    while (__hip_atomic_load(arr, __ATOMIC_RELAXED,
                             __HIP_MEMORY_SCOPE_AGENT) < e * 8u)
      __builtin_amdgcn_s_sleep(1);
  }
  __syncthreads();
}

__global__ void ftkv_init(unsigned *bar) {
  for (int i = threadIdx.x; i < 4096; i += 256) bar[i] = 0u;
}

__device__ __forceinline__ unsigned bf16rne(float x) {
  unsigned b = __float_as_uint(x);
  return (b + 0x7fffu + ((b >> 16) & 1u)) >> 16;
}

// src[K][N] fp32 -> dst dwords laid out as [K/8][N][4]
__global__ void ftkv_pack(const float *src, unsigned *dst, int K, int N) {
  int total = (K / 2) * N;
  int n4 = N * 4;
  for (int i = blockIdx.x * blockDim.x + threadIdx.x; i < total;
       i += gridDim.x * blockDim.x) {
    int k8 = i / n4, rem = i - k8 * n4;
    int col = rem >> 2, q = rem & 3;
    int r0 = 8 * k8 + 2 * q;
    dst[i] = bf16rne(src[(size_t)r0 * N + col]) |
             (bf16rne(src[(size_t)(r0 + 1) * N + col]) << 16);
  }
}

struct Smem {
  float sZ[512];
  float sP[1024];
  float sH[256];
  float sQ[64], sQB[64], sS[128], sRed[24];
};

// LN stats with light barriers; all threads get mu/rs redundantly.
__device__ __forceinline__ void lnstats(int tid, int lane, int wid, float v,
                                        float *sRed, float &mu, float &rs) {
  lbar();  // WAR: prior readers of sRed done
  if (tid < 512) {
    float s1 = waveRedSum(v), s2 = waveRedSum(v * v);
    if (lane == 0) { sRed[wid] = s1; sRed[8 + wid] = s2; }
  }
  lbar();
  float a = 0.f, c = 0.f;
#pragma unroll
  for (int i = 0; i < 8; ++i) { a += sRed[i]; c += sRed[8 + i]; }
  mu = a * (1.f / 512.f);
  float var = c * (1.f / 512.f) - mu * mu;
  rs = rsqrtf(var + 1e-5f);
}

__global__ __launch_bounds__(NTHR, 4) void ftkv_main(FtkvParams p) {
  const int bid = blockIdx.x;
  const int tid = threadIdx.x;
  const int lane = tid & 63, wid = tid >> 6;
  const int g = bid >> 3;  // batch element (group)
  const int cs = bid & 7;  // col-slice == head

  __shared__ Smem sm;

  unsigned *garr = p.bar + g * 32;
  unsigned gep = 0;

  float cw0 = p.comb_w[0], cw1 = p.comb_w[1], cw2 = p.comb_w[2],
        cw3 = p.comb_w[3], cw4 = p.comb_w[4];
  float cm = fmaxf(fmaxf(fmaxf(cw0, cw1), fmaxf(cw2, cw3)), cw4);
  float e0 = __expf(cw0 - cm), e1 = __expf(cw1 - cm), e2 = __expf(cw2 - cm),
        e3 = __expf(cw3 - cm), e4 = __expf(cw4 - cm);
  float einv = 1.0f / (e0 + e1 + e2 + e3 + e4);
  float comb0 = e0 * einv, comb1 = e1 * einv, comb2 = e2 * einv,
        comb3 = e3 * einv, comb4 = e4 * einv;

  float xr = 0.f, mr = 0.f;
  if (tid < 512) {
    xr = p.x_seq[g * D_ + tid];
    mr = comb0 * xr;
  }

  unsigned *memKb = p.memK + ((size_t)(g * H_ + cs)) * S_ * 32;
  unsigned *memVb = p.memV + ((size_t)(g * H_ + cs)) * S_ * 32;
  float *dpA = p.dpart + (size_t)g * 8 * 512;
  float *dpB = p.dpart2 + (size_t)g * 8 * 512;

  const int d6 = tid & 63, ks16 = tid >> 6;
  const int j7 = tid & 127, ds8 = tid >> 7;
  const int col9 = tid & 511, ks2 = tid >> 9;
  const int c8 = tid & 255, ksb = tid >> 8;

  for (int t = 0; t < S_; ++t) {
    for (int l = 0; l < L_; ++l) {
      const float cl = (l == 1) ? comb1 : (l == 2) ? comb2 : comb3;

      // ---- entry: apply FF(l-1) partials ----
      if (l > 0 && tid < 512) {
        float s = p.b_ff2[(l - 1) * D_ + tid];
#pragma unroll
        for (int c2 = 0; c2 < 8; ++c2) s += cload(dpB + c2 * 512 + tid);
        xr += s;
        mr += cl * xr;
      }

      // =================== Phase A: attention (t>0) =====================
      if (t > 0) {
        // ---- prefetch (independent of all LN/exchange stages) ----
        uint4 wq[4], wo[4];
        {
          const uint4 *wqp = p.wqp + (size_t)l * 64 * 512 + cs * 64 + d6;
#pragma unroll
          for (int j = 0; j < 4; ++j) wq[j] = wqp[(size_t)(ks16 * 4 + j) * 512];
          const uint4 *wop = p.wop + (size_t)l * 64 * 512 + col9;
#pragma unroll
          for (int j = 0; j < 4; ++j)
            wo[j] = wop[(size_t)(cs * 8 + ks2 * 4 + j) * 512];
        }
        uint4 mku = ((const uint4 *)(memKb + (size_t)j7 * 32))[ds8];
        int kidx = P_ - t + j7;
        kidx = kidx < 0 ? 0 : (kidx > P_ - 1 ? P_ - 1 : kidx);
        const float4 *kpp = (const float4 *)(p.kpe +
            (((size_t)l * P_ + kidx) * H_ + cs) * 64 + ds8 * 8);
        float4 kp0 = kpp[0], kp1 = kpp[1];
        unsigned mvp[8];
        {
#pragma unroll
          for (int jj = 0; jj < 8; ++jj)
            mvp[jj] = memVb[(size_t)(ks16 * 8 + jj) * 32 + (d6 >> 1)];
        }

        float mu, rs;
        lnstats(tid, lane, wid, xr, sm.sRed, mu, rs);
        if (tid < 512)
          sm.sZ[tid] = (xr - mu) * rs * p.ln1_g[l * D_ + tid] +
                       p.ln1_b[l * D_ + tid];
        lbar();
        // qproj
        {
          float acc = 0.f;
#pragma unroll
          for (int j = 0; j < 4; ++j)
            acc += dot8(&sm.sZ[8 * (ks16 * 4 + j)], wq[j]);
          sm.sP[tid] = acc;
        }
        lbar();
        if (tid < 64) {
          float q = 0.f;
#pragma unroll
          for (int ks = 0; ks < 16; ++ks) q += sm.sP[ks * 64 + tid];
          sm.sQ[tid] = q;
          sm.sQB[tid] = q + p.qpb[(l * H_ + cs) * 64 + tid];
        }
        lbar();
        // scores (unconditional; masked in softmax)
        {
          UNPK(mku.x, k0, k1); UNPK(mku.y, k2, k3);
          UNPK(mku.z, k4, k5); UNPK(mku.w, k6, k7);
          const float *qb = &sm.sQB[ds8 * 8], *qr = &sm.sQ[ds8 * 8];
          float acc =
              (qb[0] * k0 + qb[1] * k1 + qb[2] * k2 + qb[3] * k3) +
              (qb[4] * k4 + qb[5] * k5 + qb[6] * k6 + qb[7] * k7) +
              (qr[0] * kp0.x + qr[1] * kp0.y + qr[2] * kp0.z + qr[3] * kp0.w) +
              (qr[4] * kp1.x + qr[5] * kp1.y + qr[6] * kp1.z + qr[7] * kp1.w);
          sm.sP[tid] = acc;
        }
        lbar();
        // fused merge + softmax (one wave stage; r16-proven numerics)
        if (tid < 64) {
          float a0 = 0.f, a1 = 0.f;
#pragma unroll
          for (int k = 0; k < 8; ++k) {
            a0 += sm.sP[tid + k * 128];
            a1 += sm.sP[tid + 64 + k * 128];
          }
          a0 = (tid < t) ? a0 * 0.125f : -1e30f;
          a1 = (tid + 64 < t) ? a1 * 0.125f : -1e30f;
          float m = waveRedMax(fmaxf(a0, a1));
          float ee0 = __expf(a0 - m), ee1 = __expf(a1 - m);
          float s = waveRedSum(ee0 + ee1);
          sm.sS[tid] = ee0;
          sm.sS[64 + tid] = ee1;
          if (tid == 0) sm.sRed[19] = s;
        }
        lbar();
        // av (sS[j]=0 for j>=t, so unconditional)
        {
          float acc = 0.f;
#pragma unroll
          for (int jj = 0; jj < 8; ++jj) {
            UNPK(mvp[jj], v0, v1);
            float vv = (d6 & 1) ? v1 : v0;
            acc += sm.sS[ks16 * 8 + jj] * vv;
          }
          sm.sP[tid] = acc;
        }
        lbar();
        if (tid < 64) {
          float a = 0.f;
#pragma unroll
          for (int js = 0; js < 16; ++js) a += sm.sP[js * 64 + tid];
          sm.sQ[tid] = a / sm.sRed[19];
        }
        lbar();
        // Wout partial
        {
          float acc = 0.f;
#pragma unroll
          for (int j = 0; j < 4; ++j)
            acc += dot8(&sm.sQ[8 * (ks2 * 4 + j)], wo[j]);
          sm.sP[tid] = acc;
        }
        lbar();
        if (tid < 512)
          cstore(dpA + cs * 512 + tid, sm.sP[tid] + sm.sP[512 + tid]);
        gbarN(garr, gep);

        // apply Wout partials
        if (tid < 512) {
          float s = p.b_out[l * D_ + tid];
#pragma unroll
          for (int c2 = 0; c2 < 8; ++c2) s += cload(dpA + c2 * 512 + tid);
          xr += s;
        }
      }

      // =================== Phase B: LN2 + FF1 + FF2 =====================
      {
        // prefetch FF1 weights
        uint4 w1r[16];
        {
          const uint4 *w1 = p.w1p + (size_t)l * 64 * DFF_ + cs * 256 + c8;
#pragma unroll
          for (int j = 0; j < 16; ++j)
            w1r[j] = w1[(size_t)(ksb * 16 + j) * DFF_];
        }
        float mu, rs;
        lnstats(tid, lane, wid, xr, sm.sRed, mu, rs);
        if (tid < 512)
          sm.sZ[tid] = (xr - mu) * rs * p.ln2_g[l * D_ + tid] +
                       p.ln2_b[l * D_ + tid];
        lbar();
        {
          float acc = 0.f;
#pragma unroll
          for (int j = 0; j < 16; ++j)
            acc += dot8(&sm.sZ[8 * (ksb * 16 + j)], w1r[j]);
          sm.sP[tid] = acc;
        }
        // prefetch FF2 weights (overlaps sH stage)
        uint4 w2r[16];
        {
          const uint4 *w2 = p.w2p + (size_t)l * 256 * 512 + col9;
#pragma unroll
          for (int j = 0; j < 16; ++j)
            w2r[j] = w2[(size_t)(cs * 32 + ks2 * 16 + j) * 512];
        }
        lbar();
        if (tid < 256) {
          float h = ((sm.sP[tid] + sm.sP[256 + tid]) +
                     (sm.sP[512 + tid] + sm.sP[768 + tid])) +
                    p.b_ff1[l * DFF_ + cs * 256 + tid];
          sm.sH[tid] = fmaxf(h, 0.f);
        }
        lbar();
        {
          float acc = 0.f;
#pragma unroll
          for (int j = 0; j < 16; ++j)
            acc += dot8(&sm.sH[8 * (ks2 * 16 + j)], w2r[j]);
          sm.sP[tid] = acc;
        }
        lbar();
        if (tid < 512)
          cstore(dpB + cs * 512 + tid, sm.sP[tid] + sm.sP[512 + tid]);
      }
      gbarN(garr, gep);
    } // layers

    // ====== Phase E (group-local): KV slot t; out[t]; next x ====
    {
      const int kv = tid >> 9, rE = tid & 511, dE = rE & 63, ks8 = rE >> 6;
      uint4 wkv[8];
      {
        const uint4 *w4 = (kv ? p.wvp : p.wkp) + cs * 64 + dE;
#pragma unroll
        for (int j = 0; j < 8; ++j) wkv[j] = w4[(size_t)(ks8 * 8 + j) * 512];
      }
      if (tid < 512) {
        float s = p.b_ff2[3 * D_ + tid];
#pragma unroll
        for (int c2 = 0; c2 < 8; ++c2) s += cload(dpB + c2 * 512 + tid);
        xr += s;
        mr += comb4 * xr;
        sm.sZ[tid] = mr;
      }
      lbar();
      {
        float acc = 0.f;
#pragma unroll
        for (int j = 0; j < 8; ++j)
          acc += dot8(&sm.sZ[8 * (ks8 * 8 + j)], wkv[j]);
        sm.sP[tid] = acc;
      }
      lbar();
      if (tid < 128) {
        int kv2 = tid >> 6, d = tid & 63;
        float v = 0.f;
#pragma unroll
        for (int ks = 0; ks < 8; ++ks) v += sm.sP[kv2 * 512 + ks * 64 + d];
        sm.sS[tid] = v;
      }
      lbar();
      if (tid < 64) {
        int kv2 = tid >> 5, d2 = tid & 31;
        float lo = sm.sS[kv2 * 64 + 2 * d2], hi = sm.sS[kv2 * 64 + 2 * d2 + 1];
        unsigned pk = bf16rne(lo) | (bf16rne(hi) << 16);
        unsigned *dst = kv2 ? memVb : memKb;
        dst[(size_t)t * 32 + d2] = pk;
      }
      __syncthreads();  // drain KV stores: next step's prefetch reads them
      float mu, rs;
      lnstats(tid, lane, wid, xr, sm.sRed, mu, rs);
      if (tid < 512 && (tid >> 6) == cs)
        p.out[((size_t)t * B_ + g) * D_ + tid] =
            (xr - mu) * rs * p.norm_g[tid] + p.norm_b[tid];
      if (t + 1 < S_ && tid < 512) {
        xr = p.x_seq[((size_t)(t + 1) * B_ + g) * D_ + tid];
        mr = comb0 * xr;
      }
    }
    // no barrier: E is group-local; next gbarN orders the exchange
  } // t
}

extern "C" void kernel_launch(void *const *d_in, const int *in_sizes, int n_in,
                              void *d_out, int out_size, void *d_ws,
                              size_t ws_size, hipStream_t stream) {
  (void)in_sizes; (void)n_in; (void)out_size; (void)ws_size;

  FtkvParams p;
  p.x_seq  = (const float *)d_in[0];
  p.w_query = (const float *)d_in[1];
  p.qpb    = (const float *)d_in[2];
  p.kpe    = (const float *)d_in[3];
  p.w_out  = (const float *)d_in[4];
  p.b_out  = (const float *)d_in[5];
  p.ln1_g  = (const float *)d_in[6];
  p.ln1_b  = (const float *)d_in[7];
  p.ln2_g  = (const float *)d_in[8];
  p.ln2_b  = (const float *)d_in[9];
  p.w_ff1  = (const float *)d_in[10];
  p.b_ff1  = (const float *)d_in[11];
  p.w_ff2  = (const float *)d_in[12];
  p.b_ff2  = (const float *)d_in[13];
  p.norm_g = (const float *)d_in[14];
  p.norm_b = (const float *)d_in[15];
  p.comb_w = (const float *)d_in[16];
  p.w_key  = (const float *)d_in[17];
  p.w_value = (const float *)d_in[18];
  p.out = (float *)d_out;

  char *ws = (char *)d_ws;
  p.bar = (unsigned int *)ws; // 16KB
  float *f = (float *)(ws + 16384);
  p.dpart  = f; f += B_ * 8 * D_;
  p.dpart2 = f; f += B_ * 8 * D_;
  unsigned *u = (unsigned *)f;
  p.memK = u; u += B_ * H_ * S_ * 32;  // bf16-pair dwords
  p.memV = u; u += B_ * H_ * S_ * 32;
  unsigned *wqp = u; u += L_ * 256 * 512;
  unsigned *wop = u; u += L_ * 256 * 512;
  unsigned *w1p = u; u += L_ * 256 * DFF_;
  unsigned *w2p = u; u += L_ * 1024 * 512;
  unsigned *wkp = u; u += 256 * 512;
  unsigned *wvp = u; u += 256 * 512;
  p.wqp = (const uint4 *)wqp; p.wop = (const uint4 *)wop;
  p.w1p = (const uint4 *)w1p; p.w2p = (const uint4 *)w2p;
  p.wkp = (const uint4 *)wkp; p.wvp = (const uint4 *)wvp;

  ftkv_init<<<dim3(1), dim3(256), 0, stream>>>(p.bar);
  for (int l = 0; l < L_; ++l) {
    ftkv_pack<<<dim3(256), dim3(256), 0, stream>>>(
        p.w_query + (size_t)l * 512 * 512, wqp + (size_t)l * 256 * 512, 512, 512);
    ftkv_pack<<<dim3(256), dim3(256), 0, stream>>>(
        p.w_out + (size_t)l * 512 * 512, wop + (size_t)l * 256 * 512, 512, 512);
    ftkv_pack<<<dim3(512), dim3(256), 0, stream>>>(
        p.w_ff1 + (size_t)l * 512 * DFF_, w1p + (size_t)l * 256 * DFF_, 512, DFF_);
    ftkv_pack<<<dim3(512), dim3(256), 0, stream>>>(
        p.w_ff2 + (size_t)l * DFF_ * 512, w2p + (size_t)l * 1024 * 512, DFF_, 512);
  }
  ftkv_pack<<<dim3(256), dim3(256), 0, stream>>>(p.w_key, wkp, 512, 512);
  ftkv_pack<<<dim3(256), dim3(256), 0, stream>>>(p.w_value, wvp, 512, 512);
  ftkv_main<<<dim3(NBLK), dim3(NTHR), 0, stream>>>(p);
}